// Round 7
// baseline (400.060 us; speedup 1.0000x reference)
//
#include <hip/hip_runtime.h>

#define GRID_N 4096
#define NTHREADS 256

typedef float f32x4 __attribute__((ext_vector_type(4)));
typedef float f32x2 __attribute__((ext_vector_type(2)));

// packed7 layout: each row of P7 has 585 blocks of 64B; block b stores column
// pairs (sdf[r][c], sdf[r+1][c]) for c = 7b .. 7b+7 (boundary col replicated).
// A bilinear span starting at y1 lives entirely in block y1/7 -> exactly one
// 64B line per point.
#define P7_BLOCKS 585
#define P7_ROW_FLOATS (P7_BLOCKS * 16)   // 9360 floats = 37440 B per row
#define P7_ROWS (GRID_N - 1)             // 4095

__global__ void zero_loss_kernel(float* out) {
    if (threadIdx.x == 0) out[0] = 0.0f;
}

// ---------------- packed7 build ----------------
__global__ __launch_bounds__(NTHREADS) void build_p7_kernel(
    const float* __restrict__ sdf, float* __restrict__ P7)
{
    const int t = blockIdx.x * blockDim.x + threadIdx.x;  // pair-slot in row
    const int r = blockIdx.y;                             // row 0..4094
    if (t >= P7_BLOCKS * 8) return;
    const int b = t >> 3;
    const int s = t & 7;
    int c = 7 * b + s;            // column 0..4095 (b=584,s=7 -> 4095)
    float a = __builtin_nontemporal_load(&sdf[(size_t)r * GRID_N + c]);
    float d = __builtin_nontemporal_load(&sdf[(size_t)(r + 1) * GRID_N + c]);
    f32x2* row = (f32x2*)(P7 + (size_t)r * P7_ROW_FLOATS);
    f32x2 v = {a, d};
    __builtin_nontemporal_store(v, &row[t]);
}

__global__ __launch_bounds__(NTHREADS) void sdf_bilinear_p7_kernel(
    const float* __restrict__ x,
    const float* __restrict__ y,
    const float* __restrict__ P7,
    float* __restrict__ out,
    int n8)  // number of 8-point groups
{
    const int tid = blockIdx.x * blockDim.x + threadIdx.x;
    const int stride = gridDim.x * blockDim.x;
    float lsum = 0.0f;

    const f32x4* x4 = (const f32x4*)x;
    const f32x4* y4 = (const f32x4*)y;
    float* vals_out = out + 1;

    for (int i = tid; i < n8; i += stride) {
        const int g0 = 2 * i, g1 = 2 * i + 1;
        f32x4 xa = __builtin_nontemporal_load(&x4[g0]);
        f32x4 xb = __builtin_nontemporal_load(&x4[g1]);
        f32x4 ya = __builtin_nontemporal_load(&y4[g0]);
        f32x4 yb = __builtin_nontemporal_load(&y4[g1]);
        float xs[8] = {xa.x, xa.y, xa.z, xa.w, xb.x, xb.y, xb.z, xb.w};
        float ys[8] = {ya.x, ya.y, ya.z, ya.w, yb.x, yb.y, yb.z, yb.w};

        f32x2 lo[8], hi[8];
        float t[8], u[8];
#pragma unroll
        for (int k = 0; k < 8; ++k) {
            float xi = xs[k];
            float yi = ys[k];
            int x1 = min((int)xi, GRID_N - 2);   // inputs >= 0
            int y1 = min((int)yi, GRID_N - 2);
            t[k] = xi - (float)x1;
            u[k] = yi - (float)y1;
            int b = (y1 * 37450) >> 18;          // exact y1/7 for y1 < 43690
            int s = y1 - 7 * b;                  // 0..6
            const f32x2* blk =
                (const f32x2*)(P7 + (size_t)x1 * P7_ROW_FLOATS) + (b << 3) + s;
            lo[k] = blk[0];   // (v11, v21)
            hi[k] = blk[1];   // (v12, v22) — same 64B line, guaranteed
        }

        float res[8];
#pragma unroll
        for (int k = 0; k < 8; ++k) {
            float v11 = lo[k].x, v21 = lo[k].y;
            float v12 = hi[k].x, v22 = hi[k].y;
            float a = v11 + t[k] * (v21 - v11);
            float b2 = v12 + t[k] * (v22 - v12);
            float val = a + u[k] * (b2 - a);
            val = fminf(0.0f, fmaxf(-1000.0f, val));
            res[k] = val;
            lsum += val;
        }

        int base = g0 * 4;
#pragma unroll
        for (int k = 0; k < 8; ++k)
            __builtin_nontemporal_store(res[k], &vals_out[base + k]);
    }

#pragma unroll
    for (int off = 32; off > 0; off >>= 1)
        lsum += __shfl_down(lsum, off);

    __shared__ float wsum[NTHREADS / 64];
    const int lane = threadIdx.x & 63;
    const int wid = threadIdx.x >> 6;
    if (lane == 0) wsum[wid] = lsum;
    __syncthreads();
    if (threadIdx.x == 0) {
        float bsum = 0.0f;
#pragma unroll
        for (int w = 0; w < NTHREADS / 64; ++w) bsum += wsum[w];
        atomicAdd(out, bsum);
    }
}

// ---------------- pair-layout fallback (R3 kernel) ----------------
__global__ __launch_bounds__(NTHREADS) void build_pairs_kernel(
    const float* __restrict__ sdf, float* __restrict__ P)
{
    const int j = blockIdx.x * blockDim.x + threadIdx.x;
    const int i = blockIdx.y;
    float a = sdf[(size_t)i * GRID_N + j];
    float b = sdf[(size_t)(i + 1) * GRID_N + j];
    f32x2* Prow = (f32x2*)(P + (size_t)i * (2 * GRID_N));
    f32x2 v = {a, b};
    Prow[j] = v;
}

__global__ __launch_bounds__(NTHREADS) void sdf_bilinear_pairs_kernel(
    const float* __restrict__ x,
    const float* __restrict__ y,
    const float* __restrict__ P,
    float* __restrict__ out,
    int n4)
{
    const int tid = blockIdx.x * blockDim.x + threadIdx.x;
    const int stride = gridDim.x * blockDim.x;
    float lsum = 0.0f;
    const f32x4* x4 = (const f32x4*)x;
    const f32x4* y4 = (const f32x4*)y;
    float* vals_out = out + 1;

    for (int i = tid; i < n4; i += stride) {
        f32x4 xv = x4[i];
        f32x4 yv = y4[i];
        float xs[4] = {xv.x, xv.y, xv.z, xv.w};
        float ys[4] = {yv.x, yv.y, yv.z, yv.w};
        f32x2 lo[4], hi[4];
        float t[4], u[4];
#pragma unroll
        for (int k = 0; k < 4; ++k) {
            float xi = xs[k], yi = ys[k];
            int x1 = min((int)xi, GRID_N - 2);
            int y1 = min((int)yi, GRID_N - 2);
            t[k] = xi - (float)x1;
            u[k] = yi - (float)y1;
            const f32x2* Prow = (const f32x2*)(P + (size_t)x1 * (2 * GRID_N)) + y1;
            lo[k] = Prow[0];
            hi[k] = Prow[1];
        }
        float res[4];
#pragma unroll
        for (int k = 0; k < 4; ++k) {
            float v11 = lo[k].x, v21 = lo[k].y;
            float v12 = hi[k].x, v22 = hi[k].y;
            float a = v11 + t[k] * (v21 - v11);
            float b = v12 + t[k] * (v22 - v12);
            float val = a + u[k] * (b - a);
            val = fminf(0.0f, fmaxf(-1000.0f, val));
            res[k] = val;
            lsum += val;
        }
        int base = i * 4;
        vals_out[base + 0] = res[0];
        vals_out[base + 1] = res[1];
        vals_out[base + 2] = res[2];
        vals_out[base + 3] = res[3];
    }

#pragma unroll
    for (int off = 32; off > 0; off >>= 1)
        lsum += __shfl_down(lsum, off);

    __shared__ float wsum[NTHREADS / 64];
    const int lane = threadIdx.x & 63;
    const int wid = threadIdx.x >> 6;
    if (lane == 0) wsum[wid] = lsum;
    __syncthreads();
    if (threadIdx.x == 0) {
        float bsum = 0.0f;
#pragma unroll
        for (int w = 0; w < NTHREADS / 64; ++w) bsum += wsum[w];
        atomicAdd(out, bsum);
    }
}

// ---------------- direct fallback ----------------
__global__ __launch_bounds__(NTHREADS) void sdf_bilinear_direct_kernel(
    const float* __restrict__ x,
    const float* __restrict__ y,
    const float* __restrict__ sdf,
    float* __restrict__ out,
    int n4)
{
    const int tid = blockIdx.x * blockDim.x + threadIdx.x;
    const int stride = gridDim.x * blockDim.x;
    float lsum = 0.0f;
    const f32x4* x4 = (const f32x4*)x;
    const f32x4* y4 = (const f32x4*)y;
    float* vals_out = out + 1;

    for (int i = tid; i < n4; i += stride) {
        f32x4 xv = x4[i];
        f32x4 yv = y4[i];
        float xs[4] = {xv.x, xv.y, xv.z, xv.w};
        float ys[4] = {yv.x, yv.y, yv.z, yv.w};
        float res[4];
#pragma unroll
        for (int k = 0; k < 4; ++k) {
            float xi = xs[k], yi = ys[k];
            int x1 = min((int)xi, GRID_N - 2);
            int y1 = min((int)yi, GRID_N - 2);
            float t = xi - (float)x1;
            float u = yi - (float)y1;
            const float* r1 = sdf + ((size_t)x1 << 12);
            const float* r2 = r1 + GRID_N;
            float v11 = r1[y1], v12 = r1[y1 + 1];
            float v21 = r2[y1], v22 = r2[y1 + 1];
            float a = v11 + t * (v21 - v11);
            float b = v12 + t * (v22 - v12);
            float val = a + u * (b - a);
            val = fminf(0.0f, fmaxf(-1000.0f, val));
            res[k] = val;
            lsum += val;
        }
        int base = i * 4;
        vals_out[base + 0] = res[0];
        vals_out[base + 1] = res[1];
        vals_out[base + 2] = res[2];
        vals_out[base + 3] = res[3];
    }

#pragma unroll
    for (int off = 32; off > 0; off >>= 1)
        lsum += __shfl_down(lsum, off);

    __shared__ float wsum[NTHREADS / 64];
    const int lane = threadIdx.x & 63;
    const int wid = threadIdx.x >> 6;
    if (lane == 0) wsum[wid] = lsum;
    __syncthreads();
    if (threadIdx.x == 0) {
        float bsum = 0.0f;
#pragma unroll
        for (int w = 0; w < NTHREADS / 64; ++w) bsum += wsum[w];
        atomicAdd(out, bsum);
    }
}

extern "C" void kernel_launch(void* const* d_in, const int* in_sizes, int n_in,
                              void* d_out, int out_size, void* d_ws, size_t ws_size,
                              hipStream_t stream) {
    const float* x = (const float*)d_in[0];
    const float* y = (const float*)d_in[1];
    const float* sdf = (const float*)d_in[2];
    float* out = (float*)d_out;
    int n = in_sizes[0];
    int n4 = n >> 2;
    int n8 = n >> 3;

    zero_loss_kernel<<<1, 64, 0, stream>>>(out);

    const size_t p7_bytes = (size_t)P7_ROWS * P7_ROW_FLOATS * sizeof(float);      // ~153.3 MB
    const size_t pair_bytes = (size_t)(GRID_N - 1) * (2 * GRID_N) * sizeof(float); // ~134 MB

    if (ws_size >= p7_bytes) {
        float* P7 = (float*)d_ws;
        dim3 bgrid((P7_BLOCKS * 8 + NTHREADS - 1) / NTHREADS, P7_ROWS);
        build_p7_kernel<<<bgrid, NTHREADS, 0, stream>>>(sdf, P7);
        int nblocks = (n8 + NTHREADS - 1) / NTHREADS;
        sdf_bilinear_p7_kernel<<<nblocks, NTHREADS, 0, stream>>>(x, y, P7, out, n8);
    } else if (ws_size >= pair_bytes) {
        float* P = (float*)d_ws;
        dim3 bgrid(GRID_N / NTHREADS, GRID_N - 1);
        build_pairs_kernel<<<bgrid, NTHREADS, 0, stream>>>(sdf, P);
        int nblocks = (n4 + NTHREADS - 1) / NTHREADS;
        sdf_bilinear_pairs_kernel<<<nblocks, NTHREADS, 0, stream>>>(x, y, P, out, n4);
    } else {
        sdf_bilinear_direct_kernel<<<2048, NTHREADS, 0, stream>>>(x, y, sdf, out, n4);
    }
}

// Round 8
// 395.746 us; speedup vs baseline: 1.0109x; 1.0109x over previous
//
#include <hip/hip_runtime.h>

#define GRID_N 4096
#define NTHREADS 256

typedef float f32x4 __attribute__((ext_vector_type(4)));
typedef float f32x2 __attribute__((ext_vector_type(2)));

// packed7 layout: each row of P7 has 585 blocks of 64B; block b stores column
// pairs (sdf[r][c], sdf[r+1][c]) for c = 7b .. 7b+7 (boundary col replicated).
// A bilinear span starting at y1 lives entirely in block y1/7 -> exactly one
// 64B line per point.
#define P7_BLOCKS 585
#define P7_ROW_FLOATS (P7_BLOCKS * 16)   // 9360 floats = 37440 B per row
#define P7_ROWS (GRID_N - 1)             // 4095

__global__ void zero_loss_kernel(float* out) {
    if (threadIdx.x == 0) out[0] = 0.0f;
}

// ---------------- packed7 build ----------------
// sdf reads: nontemporal (read once, don't pollute LLC).
// P7 stores: NORMAL allocating stores — we WANT P7 resident in the 256MB
// Infinity Cache so the gather phase hits LLC instead of random-64B HBM.
__global__ __launch_bounds__(NTHREADS) void build_p7_kernel(
    const float* __restrict__ sdf, float* __restrict__ P7)
{
    const int t = blockIdx.x * blockDim.x + threadIdx.x;  // pair-slot in row
    const int r = blockIdx.y;                             // row 0..4094
    if (t >= P7_BLOCKS * 8) return;
    const int b = t >> 3;
    const int s = t & 7;
    int c = 7 * b + s;            // column 0..4095 (b=584,s=7 -> 4095)
    float a = __builtin_nontemporal_load(&sdf[(size_t)r * GRID_N + c]);
    float d = __builtin_nontemporal_load(&sdf[(size_t)(r + 1) * GRID_N + c]);
    f32x2* row = (f32x2*)(P7 + (size_t)r * P7_ROW_FLOATS);
    f32x2 v = {a, d};
    row[t] = v;   // allocating store -> LLC-resident P7
}

__global__ __launch_bounds__(NTHREADS) void sdf_bilinear_p7_kernel(
    const float* __restrict__ x,
    const float* __restrict__ y,
    const float* __restrict__ P7,
    float* __restrict__ out,
    int n8)  // number of 8-point groups
{
    const int tid = blockIdx.x * blockDim.x + threadIdx.x;
    const int stride = gridDim.x * blockDim.x;
    float lsum = 0.0f;

    const f32x4* x4 = (const f32x4*)x;
    const f32x4* y4 = (const f32x4*)y;
    float* vals_out = out + 1;

    for (int i = tid; i < n8; i += stride) {
        const int g0 = 2 * i, g1 = 2 * i + 1;
        f32x4 xa = __builtin_nontemporal_load(&x4[g0]);
        f32x4 xb = __builtin_nontemporal_load(&x4[g1]);
        f32x4 ya = __builtin_nontemporal_load(&y4[g0]);
        f32x4 yb = __builtin_nontemporal_load(&y4[g1]);
        float xs[8] = {xa.x, xa.y, xa.z, xa.w, xb.x, xb.y, xb.z, xb.w};
        float ys[8] = {ya.x, ya.y, ya.z, ya.w, yb.x, yb.y, yb.z, yb.w};

        f32x2 lo[8], hi[8];
        float t[8], u[8];
#pragma unroll
        for (int k = 0; k < 8; ++k) {
            float xi = xs[k];
            float yi = ys[k];
            int x1 = min((int)xi, GRID_N - 2);   // inputs >= 0
            int y1 = min((int)yi, GRID_N - 2);
            t[k] = xi - (float)x1;
            u[k] = yi - (float)y1;
            int b = (y1 * 37450) >> 18;          // exact y1/7 for y1 < 43690
            int s = y1 - 7 * b;                  // 0..6
            const f32x2* blk =
                (const f32x2*)(P7 + (size_t)x1 * P7_ROW_FLOATS) + (b << 3) + s;
            lo[k] = blk[0];   // (v11, v21)
            hi[k] = blk[1];   // (v12, v22) — same 64B line, guaranteed
        }

        float res[8];
#pragma unroll
        for (int k = 0; k < 8; ++k) {
            float v11 = lo[k].x, v21 = lo[k].y;
            float v12 = hi[k].x, v22 = hi[k].y;
            float a = v11 + t[k] * (v21 - v11);
            float b2 = v12 + t[k] * (v22 - v12);
            float val = a + u[k] * (b2 - a);
            val = fminf(0.0f, fmaxf(-1000.0f, val));
            res[k] = val;
            lsum += val;
        }

        int base = g0 * 4;
#pragma unroll
        for (int k = 0; k < 8; ++k)
            __builtin_nontemporal_store(res[k], &vals_out[base + k]);
    }

#pragma unroll
    for (int off = 32; off > 0; off >>= 1)
        lsum += __shfl_down(lsum, off);

    __shared__ float wsum[NTHREADS / 64];
    const int lane = threadIdx.x & 63;
    const int wid = threadIdx.x >> 6;
    if (lane == 0) wsum[wid] = lsum;
    __syncthreads();
    if (threadIdx.x == 0) {
        float bsum = 0.0f;
#pragma unroll
        for (int w = 0; w < NTHREADS / 64; ++w) bsum += wsum[w];
        atomicAdd(out, bsum);
    }
}

// ---------------- pair-layout fallback ----------------
__global__ __launch_bounds__(NTHREADS) void build_pairs_kernel(
    const float* __restrict__ sdf, float* __restrict__ P)
{
    const int j = blockIdx.x * blockDim.x + threadIdx.x;
    const int i = blockIdx.y;
    float a = sdf[(size_t)i * GRID_N + j];
    float b = sdf[(size_t)(i + 1) * GRID_N + j];
    f32x2* Prow = (f32x2*)(P + (size_t)i * (2 * GRID_N));
    f32x2 v = {a, b};
    Prow[j] = v;
}

__global__ __launch_bounds__(NTHREADS) void sdf_bilinear_pairs_kernel(
    const float* __restrict__ x,
    const float* __restrict__ y,
    const float* __restrict__ P,
    float* __restrict__ out,
    int n4)
{
    const int tid = blockIdx.x * blockDim.x + threadIdx.x;
    const int stride = gridDim.x * blockDim.x;
    float lsum = 0.0f;
    const f32x4* x4 = (const f32x4*)x;
    const f32x4* y4 = (const f32x4*)y;
    float* vals_out = out + 1;

    for (int i = tid; i < n4; i += stride) {
        f32x4 xv = x4[i];
        f32x4 yv = y4[i];
        float xs[4] = {xv.x, xv.y, xv.z, xv.w};
        float ys[4] = {yv.x, yv.y, yv.z, yv.w};
        f32x2 lo[4], hi[4];
        float t[4], u[4];
#pragma unroll
        for (int k = 0; k < 4; ++k) {
            float xi = xs[k], yi = ys[k];
            int x1 = min((int)xi, GRID_N - 2);
            int y1 = min((int)yi, GRID_N - 2);
            t[k] = xi - (float)x1;
            u[k] = yi - (float)y1;
            const f32x2* Prow = (const f32x2*)(P + (size_t)x1 * (2 * GRID_N)) + y1;
            lo[k] = Prow[0];
            hi[k] = Prow[1];
        }
        float res[4];
#pragma unroll
        for (int k = 0; k < 4; ++k) {
            float v11 = lo[k].x, v21 = lo[k].y;
            float v12 = hi[k].x, v22 = hi[k].y;
            float a = v11 + t[k] * (v21 - v11);
            float b = v12 + t[k] * (v22 - v12);
            float val = a + u[k] * (b - a);
            val = fminf(0.0f, fmaxf(-1000.0f, val));
            res[k] = val;
            lsum += val;
        }
        int base = i * 4;
        vals_out[base + 0] = res[0];
        vals_out[base + 1] = res[1];
        vals_out[base + 2] = res[2];
        vals_out[base + 3] = res[3];
    }

#pragma unroll
    for (int off = 32; off > 0; off >>= 1)
        lsum += __shfl_down(lsum, off);

    __shared__ float wsum[NTHREADS / 64];
    const int lane = threadIdx.x & 63;
    const int wid = threadIdx.x >> 6;
    if (lane == 0) wsum[wid] = lsum;
    __syncthreads();
    if (threadIdx.x == 0) {
        float bsum = 0.0f;
#pragma unroll
        for (int w = 0; w < NTHREADS / 64; ++w) bsum += wsum[w];
        atomicAdd(out, bsum);
    }
}

// ---------------- direct fallback ----------------
__global__ __launch_bounds__(NTHREADS) void sdf_bilinear_direct_kernel(
    const float* __restrict__ x,
    const float* __restrict__ y,
    const float* __restrict__ sdf,
    float* __restrict__ out,
    int n4)
{
    const int tid = blockIdx.x * blockDim.x + threadIdx.x;
    const int stride = gridDim.x * blockDim.x;
    float lsum = 0.0f;
    const f32x4* x4 = (const f32x4*)x;
    const f32x4* y4 = (const f32x4*)y;
    float* vals_out = out + 1;

    for (int i = tid; i < n4; i += stride) {
        f32x4 xv = x4[i];
        f32x4 yv = y4[i];
        float xs[4] = {xv.x, xv.y, xv.z, xv.w};
        float ys[4] = {yv.x, yv.y, yv.z, yv.w};
        float res[4];
#pragma unroll
        for (int k = 0; k < 4; ++k) {
            float xi = xs[k], yi = ys[k];
            int x1 = min((int)xi, GRID_N - 2);
            int y1 = min((int)yi, GRID_N - 2);
            float t = xi - (float)x1;
            float u = yi - (float)y1;
            const float* r1 = sdf + ((size_t)x1 << 12);
            const float* r2 = r1 + GRID_N;
            float v11 = r1[y1], v12 = r1[y1 + 1];
            float v21 = r2[y1], v22 = r2[y1 + 1];
            float a = v11 + t * (v21 - v11);
            float b = v12 + t * (v22 - v12);
            float val = a + u * (b - a);
            val = fminf(0.0f, fmaxf(-1000.0f, val));
            res[k] = val;
            lsum += val;
        }
        int base = i * 4;
        vals_out[base + 0] = res[0];
        vals_out[base + 1] = res[1];
        vals_out[base + 2] = res[2];
        vals_out[base + 3] = res[3];
    }

#pragma unroll
    for (int off = 32; off > 0; off >>= 1)
        lsum += __shfl_down(lsum, off);

    __shared__ float wsum[NTHREADS / 64];
    const int lane = threadIdx.x & 63;
    const int wid = threadIdx.x >> 6;
    if (lane == 0) wsum[wid] = lsum;
    __syncthreads();
    if (threadIdx.x == 0) {
        float bsum = 0.0f;
#pragma unroll
        for (int w = 0; w < NTHREADS / 64; ++w) bsum += wsum[w];
        atomicAdd(out, bsum);
    }
}

extern "C" void kernel_launch(void* const* d_in, const int* in_sizes, int n_in,
                              void* d_out, int out_size, void* d_ws, size_t ws_size,
                              hipStream_t stream) {
    const float* x = (const float*)d_in[0];
    const float* y = (const float*)d_in[1];
    const float* sdf = (const float*)d_in[2];
    float* out = (float*)d_out;
    int n = in_sizes[0];
    int n4 = n >> 2;
    int n8 = n >> 3;

    zero_loss_kernel<<<1, 64, 0, stream>>>(out);

    const size_t p7_bytes = (size_t)P7_ROWS * P7_ROW_FLOATS * sizeof(float);      // ~153.3 MB
    const size_t pair_bytes = (size_t)(GRID_N - 1) * (2 * GRID_N) * sizeof(float); // ~134 MB

    if (ws_size >= p7_bytes) {
        float* P7 = (float*)d_ws;
        dim3 bgrid((P7_BLOCKS * 8 + NTHREADS - 1) / NTHREADS, P7_ROWS);
        build_p7_kernel<<<bgrid, NTHREADS, 0, stream>>>(sdf, P7);
        int nblocks = (n8 + NTHREADS - 1) / NTHREADS;
        sdf_bilinear_p7_kernel<<<nblocks, NTHREADS, 0, stream>>>(x, y, P7, out, n8);
    } else if (ws_size >= pair_bytes) {
        float* P = (float*)d_ws;
        dim3 bgrid(GRID_N / NTHREADS, GRID_N - 1);
        build_pairs_kernel<<<bgrid, NTHREADS, 0, stream>>>(sdf, P);
        int nblocks = (n4 + NTHREADS - 1) / NTHREADS;
        sdf_bilinear_pairs_kernel<<<nblocks, NTHREADS, 0, stream>>>(x, y, P, out, n4);
    } else {
        sdf_bilinear_direct_kernel<<<2048, NTHREADS, 0, stream>>>(x, y, sdf, out, n4);
    }
}